// Round 7
// baseline (21503.984 us; speedup 1.0000x reference)
//
#include <hip/hip_runtime.h>
#include <hip/hip_bf16.h>

typedef __hip_bfloat16 bf16;
typedef unsigned long long u64;
typedef unsigned int u32;
typedef unsigned short u16;
using short8 = __attribute__((ext_vector_type(8))) short;   // 8 bf16 MFMA A/B frag
using f32x4  = __attribute__((ext_vector_type(4))) float;   // MFMA C/D frag

#define T_STEPS 2048
#define IDIM    256
#define HDIM    512
#define NB0     32
#define NBLK    64
#define R0      8                 // h0 ring slots
#define R1      2                 // h1 ring slots (dataflow-safe: writer at p has observed
                                  // h1[p-1], which implies all peers finished reading h1[p-2])
#define HW      (32 * 512)        // u32 words per h slot (value<<16 | epoch)
#define LROW    528               // LDS row stride (bf16); 1056B == 8 dw mod 32 (conflict floor)

__device__ __forceinline__ float sigm(float x) { return 1.0f / (1.0f + __expf(-x)); }
__device__ __forceinline__ float tanh_f(float x) {
  x = fminf(fmaxf(x, -15.f), 15.f);
  float e = __expf(2.f * x);
  return (e - 1.f) / (e + 1.f);
}
__device__ __forceinline__ u16 bfbits(float f) {
  bf16 b = __float2bfloat16(f); u16 s; __builtin_memcpy(&s, &b, 2); return s;
}
__device__ __forceinline__ short8 cvt8(const float* __restrict__ p) {
  float4 lo = *(const float4*)(const void*)p;
  float4 hi = *(const float4*)(const void*)(p + 4);
  short8 r;
  r[0] = (short)bfbits(lo.x); r[1] = (short)bfbits(lo.y); r[2] = (short)bfbits(lo.z); r[3] = (short)bfbits(lo.w);
  r[4] = (short)bfbits(hi.x); r[5] = (short)bfbits(hi.y); r[6] = (short)bfbits(hi.z); r[7] = (short)bfbits(hi.w);
  return r;
}

// LLC-coherent (L1/L2-bypassing) accesses: agent-scope relaxed atomics.
__device__ __forceinline__ u64 ldg8(const u64* p) {
  return __hip_atomic_load(p, __ATOMIC_RELAXED, __HIP_MEMORY_SCOPE_AGENT);
}
__device__ __forceinline__ u32 ldg4(const u32* p) {
  return __hip_atomic_load(p, __ATOMIC_RELAXED, __HIP_MEMORY_SCOPE_AGENT);
}
__device__ __forceinline__ void stg4(u32* p, u32 v) {
  __hip_atomic_store(p, v, __ATOMIC_RELAXED, __HIP_MEMORY_SCOPE_AGENT);
}

// Write one validated u64 chunk (2 tagged words) into LDS as a packed bf16 pair.
__device__ __forceinline__ void ldsw(bf16* dst, int c, u64 v) {
  u32 lo = (u32)v, hi = (u32)(v >> 32);
  u32 packed = (lo >> 16) | (hi & 0xffff0000u);   // [val1|val0]
  *(u32*)(void*)(dst + (c >> 8) * LROW + (c & 255) * 2) = packed;
}

#define TAGMASK 0x0000ffff0000ffffULL

// Poll-stage one tagged 64KB h slot -> LDS. 256 threads x 32 u64 chunks, swept in
// 4 groups of 8 so only 16 VGPRs of staging data are live (NO SPILLS — R5's 256-VGPR
// scratch traffic sat on the critical path). The loads ARE the sync: re-issue
// (mask-parallel) any chunk whose embedded epochs != tag. Poison 0xAAAA never matches.
__device__ __forceinline__ void stage1(const u32* __restrict__ src, bf16* dst, int tid, u32 tag) {
  const u64* s = (const u64*)(const void*)src;
  const u64 tt = ((u64)tag << 32) | tag;
#pragma unroll
  for (int g = 0; g < 4; g++) {
    const int base = tid + g * 8 * 256;
    u64 v[8];
#pragma unroll
    for (int i = 0; i < 8; i++) v[i] = ldg8(s + base + i * 256);
    unsigned bad = 0xffu;
    while (bad) {
      unsigned nb = 0;
#pragma unroll
      for (int i = 0; i < 8; i++)
        if (bad & (1u << i)) {
          if ((v[i] & TAGMASK) != tt) { v[i] = ldg8(s + base + i * 256); nb |= 1u << i; }
        }
      bad = nb;
    }
#pragma unroll
    for (int i = 0; i < 8; i++) ldsw(dst, base + i * 256, v[i]);
  }
}

__device__ __forceinline__ int wave_min_i(int v) {
#pragma unroll
  for (int off = 32; off > 0; off >>= 1) {
    int o = __shfl_xor(v, off, 64);
    v = v < o ? v : o;
  }
  return v;
}

#define MFMA(a, b, c) __builtin_amdgcn_mfma_f32_16x16x32_bf16((a), (b), (c), 0, 0, 0)

__global__ void __launch_bounds__(256, 1) lstm_persistent(
    const float* __restrict__ x,
    const float* __restrict__ Wih0, const float* __restrict__ Whh0,
    const float* __restrict__ bih0, const float* __restrict__ bhh0,
    const float* __restrict__ Wih1, const float* __restrict__ Whh1,
    const float* __restrict__ bih1, const float* __restrict__ bhh1,
    const float* __restrict__ fcw, const float* __restrict__ fcb,
    float* __restrict__ out,
    u32* __restrict__ prog,        // 32 x 128B l1 read-progress lines
    u32* __restrict__ h0ring,      // R0 x HW tagged words
    u32* __restrict__ h1ring) {    // R1 x HW tagged words
  __shared__ __align__(16) bf16 lds_h0[32 * LROW];
  __shared__ __align__(16) bf16 lds_h1[32 * LROW];

  const int tid  = threadIdx.x;
  const int w    = tid >> 6, lane = tid & 63;
  const int q    = lane >> 4, m = lane & 15, q8 = q * 8;
  const int bx   = (int)blockIdx.x;
  const bool l0  = (bx < NB0);
  const int blk  = l0 ? bx : bx - NB0;
  const int jb   = blk * 16 + w * 4;
  const int unit = jb + (m >> 2), gate = m & 3;
  const int wrow = gate * HDIM + unit;
  const int ju   = jb + q;

  // ---- Preload weights (f32 -> bf16 A-frags) into VGPRs ----
  short8 A[32];
  f32x4 bias;
  if (l0) {
#pragma unroll
    for (int kc = 0; kc < 8; kc++)  A[kc]      = cvt8(Wih0 + wrow * IDIM + kc * 32 + q8);
#pragma unroll
    for (int kc = 0; kc < 16; kc++) A[8 + kc]  = cvt8(Whh0 + wrow * HDIM + kc * 32 + q8);
#pragma unroll
    for (int r = 0; r < 4; r++)
      bias[r] = bih0[r * HDIM + ju] + bhh0[r * HDIM + ju];
  } else {
#pragma unroll
    for (int kc = 0; kc < 16; kc++) A[kc]      = cvt8(Wih1 + wrow * HDIM + kc * 32 + q8);
#pragma unroll
    for (int kc = 0; kc < 16; kc++) A[16 + kc] = cvt8(Whh1 + wrow * HDIM + kc * 32 + q8);
#pragma unroll
    for (int r = 0; r < 4; r++)
      bias[r] = bih1[r * HDIM + ju] + bhh1[r * HDIM + ju];
  }

  float c_a = 0.f, c_b = 0.f;

  if (l0) {
    // prefetch xg[0]
    f32x4 an0 = bias, an1 = bias;
    {
      const float* xa = x + (size_t)m * (T_STEPS * IDIM) + q8;
      const float* xb = xa + (size_t)16 * (T_STEPS * IDIM);
#pragma unroll
      for (int kc = 0; kc < 8; kc++) {
        an0 = MFMA(A[kc], cvt8(xa + kc * 32), an0);
        an1 = MFMA(A[kc], cvt8(xb + kc * 32), an1);
      }
    }
    int est = 0;   // cached min l1 read-progress
    for (int p = 0; p < T_STEPS; ++p) {
      if (p > 0) {
        stage1(h0ring + ((p - 1) & (R0 - 1)) * HW, lds_h0, tid, (u32)p);   // h0[p-1], tag p
        __syncthreads();
      }
      f32x4 a0 = an0, a1 = an1;                       // bias + Wih0 x[p]
      if (p > 0) {
#pragma unroll
        for (int kc = 0; kc < 16; kc++) {
          short8 b0 = *(const short8*)(const void*)(lds_h0 + m * LROW + kc * 32 + q8);
          short8 b1 = *(const short8*)(const void*)(lds_h0 + (m + 16) * LROW + kc * 32 + q8);
          a0 = MFMA(A[8 + kc], b0, a0);
          a1 = MFMA(A[8 + kc], b1, a1);
        }
      }
      float ia = sigm(a0[0]), fa = sigm(a0[1]), ga = tanh_f(a0[2]), oa = sigm(a0[3]);
      c_a = fa * c_a + ia * ga;
      float ib = sigm(a1[0]), fb = sigm(a1[1]), gb = tanh_f(a1[2]), ob = sigm(a1[3]);
      c_b = fb * c_b + ib * gb;
      u16 hb_a = bfbits(oa * tanh_f(c_a));
      u16 hb_b = bfbits(ob * tanh_f(c_b));

      // flow control: slot p%R0 currently holds h0[p-R0] (l1 reader posts prog p-R0+1)
      if (p >= R0) {
        int needed = p - R0 + 1;
        if (est < needed) {
          int mn;
          do {
            u32 pr = ldg4(prog + (lane & 31) * 32);
            mn = wave_min_i((int)pr);
          } while (mn < needed);
          est = mn;
        }
      }
      u32 tag = (u32)(p + 1);
      u32* hw = h0ring + (p & (R0 - 1)) * HW;
      stg4(hw + m * HDIM + ju,        ((u32)hb_a << 16) | tag);
      stg4(hw + (m + 16) * HDIM + ju, ((u32)hb_b << 16) | tag);

      if (p + 1 < T_STEPS) {                          // prefetch xg[p+1] (off critical path)
        an0 = bias; an1 = bias;
        const float* xa = x + (size_t)m * (T_STEPS * IDIM) + (size_t)(p + 1) * IDIM + q8;
        const float* xb = xa + (size_t)16 * (T_STEPS * IDIM);
#pragma unroll
        for (int kc = 0; kc < 8; kc++) {
          an0 = MFMA(A[kc], cvt8(xa + kc * 32), an0);
          an1 = MFMA(A[kc], cvt8(xb + kc * 32), an1);
        }
      }
      __syncthreads();   // LDS reads done before next iteration's staging overwrites
    }

    // ---- FC epilogue: blocks 0..15 poll h1[T-1] tags directly ----
    if (bx < 16) {
      stage1(h1ring + ((T_STEPS - 1) & (R1 - 1)) * HW, lds_h0, tid, (u32)T_STEPS);
      __syncthreads();
      if (w == 0) {
        const int obase = bx * 16;
        f32x4 a0, a1;
#pragma unroll
        for (int r = 0; r < 4; r++) {
          float bb = fcb[obase + 4 * q + r];
          a0[r] = bb; a1[r] = bb;
        }
        const float* Ar = fcw + (size_t)(obase + m) * HDIM + q8;
#pragma unroll
        for (int kc = 0; kc < 16; kc++) {
          short8 af = cvt8(Ar + kc * 32);
          short8 b0 = *(const short8*)(const void*)(lds_h0 + m * LROW + kc * 32 + q8);
          short8 b1 = *(const short8*)(const void*)(lds_h0 + (m + 16) * LROW + kc * 32 + q8);
          a0 = MFMA(af, b0, a0);
          a1 = MFMA(af, b1, a1);
        }
#pragma unroll
        for (int r = 0; r < 4; r++) {
          out[m * 256 + obase + 4 * q + r]        = a0[r];
          out[(m + 16) * 256 + obase + 4 * q + r] = a1[r];
        }
      }
    }
  } else {
    // ---- layer 1: pure dataflow consumer/producer ----
    for (int p = 0; p < T_STEPS; ++p) {
      stage1(h0ring + (p & (R0 - 1)) * HW, lds_h0, tid, (u32)(p + 1));    // h0[p]
      __syncthreads();
      if (tid == 0) stg4(prog + blk * 32, (u32)(p + 1));                  // done reading h0[p]
      if (p > 0) {
        stage1(h1ring + ((p - 1) & (R1 - 1)) * HW, lds_h1, tid, (u32)p);  // h1[p-1]
        __syncthreads();
      }

      f32x4 a0 = bias, a1 = bias;
#pragma unroll
      for (int kc = 0; kc < 16; kc++) {
        short8 b0 = *(const short8*)(const void*)(lds_h0 + m * LROW + kc * 32 + q8);
        short8 b1 = *(const short8*)(const void*)(lds_h0 + (m + 16) * LROW + kc * 32 + q8);
        a0 = MFMA(A[kc], b0, a0);
        a1 = MFMA(A[kc], b1, a1);
      }
      if (p > 0) {
#pragma unroll
        for (int kc = 0; kc < 16; kc++) {
          short8 b0 = *(const short8*)(const void*)(lds_h1 + m * LROW + kc * 32 + q8);
          short8 b1 = *(const short8*)(const void*)(lds_h1 + (m + 16) * LROW + kc * 32 + q8);
          a0 = MFMA(A[16 + kc], b0, a0);
          a1 = MFMA(A[16 + kc], b1, a1);
        }
      }
      float ia = sigm(a0[0]), fa = sigm(a0[1]), ga = tanh_f(a0[2]), oa = sigm(a0[3]);
      c_a = fa * c_a + ia * ga;
      float ib = sigm(a1[0]), fb = sigm(a1[1]), gb = tanh_f(a1[2]), ob = sigm(a1[3]);
      c_b = fb * c_b + ib * gb;
      u32 tag = (u32)(p + 1);
      u32* hw = h1ring + (p & (R1 - 1)) * HW;
      stg4(hw + m * HDIM + ju,        ((u32)bfbits(oa * tanh_f(c_a)) << 16) | tag);
      stg4(hw + (m + 16) * HDIM + ju, ((u32)bfbits(ob * tanh_f(c_b)) << 16) | tag);
      __syncthreads();   // LDS reads done before next iteration's staging overwrites
    }
  }
}

extern "C" void kernel_launch(void* const* d_in, const int* in_sizes, int n_in,
                              void* d_out, int out_size, void* d_ws, size_t ws_size,
                              hipStream_t stream) {
  const float* x    = (const float*)d_in[0];
  const float* Wih0 = (const float*)d_in[1];
  const float* Whh0 = (const float*)d_in[2];
  const float* bih0 = (const float*)d_in[3];
  const float* bhh0 = (const float*)d_in[4];
  const float* Wih1 = (const float*)d_in[5];
  const float* Whh1 = (const float*)d_in[6];
  const float* bih1 = (const float*)d_in[7];
  const float* bhh1 = (const float*)d_in[8];
  const float* fcw  = (const float*)d_in[9];
  const float* fcb  = (const float*)d_in[10];

  // ws: [0,4K) l1 progress lines (zeroed); [4K, 4K+512K) h0 ring; then 128K h1 ring.
  // Ring slots NOT zeroed: 0xAA poison -> epoch fields 0xAAAA, never equals a tag in
  // [1,2048] -> consumers spin until real data lands.
  u32* prog   = (u32*)d_ws;
  u32* h0ring = (u32*)((char*)d_ws + 4096);
  u32* h1ring = (u32*)((char*)d_ws + 4096 + (size_t)R0 * HW * sizeof(u32));

  hipMemsetAsync(d_ws, 0, 4096, stream);   // progress counters start at 0

  hipLaunchKernelGGL(lstm_persistent, dim3(NBLK), dim3(256), 0, stream,
                     x, Wih0, Whh0, bih0, bhh0, Wih1, Whh1, bih1, bhh1, fcw, fcb,
                     (float*)d_out, prog, h0ring, h1ring);
}